// Round 4
// baseline (2551.332 us; speedup 1.0000x reference)
//
#include <hip/hip_runtime.h>
#include <hip/hip_bf16.h>
#include <math.h>

// Shapes (fixed by the problem)
#define Bb   64
#define Nn   40
#define Ww   256
#define FIN  64
#define Hh   4
#define Dd   32
#define Cc   128
#define NT   7
#define FC   128
#define WT   61          // receptive field of the TCN stack
#define W0   195         // first needed global timestep (255-60)
#define PSTRIDE 520      // LDS panel stride (ushorts): 64 rows x 8 + 8 pad

// workspace layout (byte offsets). seq stored as split bf16 (hi+lo),
// global layout per row r: [16 panels][61 rows][8 ushorts]  (7808 ushorts)
#define SEQHI_OFF  0u
#define SEQ_BYTES  (448u * WT * Cc * 2u)             // 6,995,968 B
#define SEQLO_OFF  (SEQHI_OFF + SEQ_BYTES)
#define WBH_OFF    (SEQLO_OFF + SEQ_BYTES)           // frag-ordered bf16 weights (hi)
#define WB_BYTES   (8u * 4u * 24u * 64u * 8u * 2u)   // 786,432 B
#define WBL_OFF    (WBH_OFF + WB_BYTES)
#define PSB_OFF    (WBL_OFF + WB_BYTES)              // f32 bias[8][128]
#define PSS_OFF    (PSB_OFF + 4096u)                 // f32 scale[8][128]
#define PSH_OFF    (PSS_OFF + 4096u)                 // f32 shift[8][128]
#define WPHASE_US  49152u                            // ushorts per phase in WBH/WBL

typedef __attribute__((ext_vector_type(8)))  short short8;
typedef __attribute__((ext_vector_type(16))) float f32x16;

__device__ __forceinline__ float gelu_exact(float v) {
    return 0.5f * v * (1.0f + erff(v * 0.70710678118654752440f));
}
__device__ __forceinline__ float b2f(ushort u) {
    union { uint i; float f; } c; c.i = ((uint)u) << 16; return c.f;
}
__device__ __forceinline__ void split_bf16(float v, ushort& h, ushort& l) {
    __hip_bfloat16 bh = __float2bfloat16(v);
    float fh = __bfloat162float(bh);
    __hip_bfloat16 bl = __float2bfloat16(v - fh);
    h = *(ushort*)&bh; l = *(ushort*)&bl;
}

// ---------------------------------------------------------------------------
// Prep: split conv weights into bf16 hi/lo in MFMA-B-fragment order + BN fold.
// ---------------------------------------------------------------------------
__global__ __launch_bounds__(256) void prep_kernel(
    const float* __restrict__ c1w, const float* __restrict__ c1b,
    const float* __restrict__ c2w, const float* __restrict__ c2b,
    const float* __restrict__ bn1s, const float* __restrict__ bn1b,
    const float* __restrict__ bn1m, const float* __restrict__ bn1v,
    const float* __restrict__ bn2s, const float* __restrict__ bn2b,
    const float* __restrict__ bn2m, const float* __restrict__ bn2v,
    char* __restrict__ ws)
{
    if (blockIdx.x < 192) {
        const int t = blockIdx.x * 256 + threadIdx.x;   // [0, 49152)
        const int lane  = t & 63;
        const int kstep = (t >> 6) % 24;
        const int nt    = ((t >> 6) / 24) & 3;
        const int p     = (t >> 6) / 96;
        const int l = p >> 1, cv = p & 1;
        const int co = nt * 32 + (lane & 31);
        const float* wsrc = cv ? c2w : c1w;
        ushort* wbh = (ushort*)(ws + WBH_OFF);
        ushort* wbl = (ushort*)(ws + WBL_OFF);
#pragma unroll
        for (int j = 0; j < 8; ++j) {
            const int k  = kstep * 16 + ((lane >> 5) << 3) + j;
            const int kk = k >> 7, ci = k & 127;
            const float w = wsrc[((size_t)(l * Cc + co) * Cc + ci) * 3 + kk];
            ushort h, lo; split_bf16(w, h, lo);
            wbh[(size_t)t * 8 + j] = h;
            wbl[(size_t)t * 8 + j] = lo;
        }
    } else {
        float* psb = (float*)(ws + PSB_OFF);
        float* pss = (float*)(ws + PSS_OFF);
        float* psh = (float*)(ws + PSH_OFF);
        for (int idx = threadIdx.x; idx < 1024; idx += 256) {
            const int p = idx >> 7, co = idx & 127;
            const int l = p >> 1, cv = p & 1;
            const int lc = l * Cc + co;
            const float s  = cv ? bn2s[lc] : bn1s[lc];
            const float bb = cv ? bn2b[lc] : bn1b[lc];
            const float m  = cv ? bn2m[lc] : bn1m[lc];
            const float vv = cv ? bn2v[lc] : bn1v[lc];
            const float cb = cv ? c2b[lc] : c1b[lc];
            const float scale = s * rsqrtf(vv + 1e-5f);
            pss[idx] = scale;
            psh[idx] = bb - m * scale;
            psb[idx] = cb;
        }
    }
}

// ---------------------------------------------------------------------------
// Kernel 1: per (b, tau): GAT + LayerNorm. 512 threads, 1 co/thread,
// K split in halves so weights stay register-resident (~60 VGPR).
// Writes seq in K2's fragment-panel order.
// ---------------------------------------------------------------------------
__global__ __launch_bounds__(512, 6) void gat_ln_kernel(
    const float* __restrict__ x, const float* __restrict__ adj,
    const float* __restrict__ gat_w, const float* __restrict__ a_src,
    const float* __restrict__ a_dst, const float* __restrict__ ln_g,
    const float* __restrict__ ln_b,
    ushort* __restrict__ seq_hi, ushort* __restrict__ seq_lo)
{
    __shared__ __align__(16) float smem[Nn * FIN];   // x, later attn+g (overlay)
    __shared__ __align__(16) float h_lds[Nn * Cc];
    __shared__ __align__(16) float e_lds[2 * Nn * Hh];

    float* x_lds    = smem;
    float* attn_lds = smem;                 // [NT*Hh*Nn] = 1120 floats
    float* g_lds    = smem + NT * Hh * Nn;  // [NT*Cc]    =  896 floats

    const int tid = threadIdx.x;
    const int blk = blockIdx.x;
    const int b   = blk / WT;
    const int tau = blk % WT;
    const int w   = W0 + tau;

    for (int idx = tid; idx < Nn * FIN; idx += 512) {
        const int n = idx >> 6, f = idx & 63;
        x_lds[idx] = x[((b * Nn + n) * Ww + w) * FIN + f];
    }
    __syncthreads();

    // ---- h-GEMM: co = tid&127, 10 n per thread, K in 2 halves of 32 ----
    {
        const int co  = tid & 127;
        const int nh  = tid >> 7;
        const int l32 = tid & 31;
        float acc[10];
#pragma unroll
        for (int i = 0; i < 10; ++i) acc[i] = 0.f;
#pragma unroll
        for (int kh = 0; kh < 2; ++kh) {
            float wreg[32];
            const float4* wr = (const float4*)(gat_w + co * FIN + kh * 32);
#pragma unroll
            for (int i = 0; i < 8; ++i) ((float4*)wreg)[i] = wr[i];
#pragma unroll
            for (int ni = 0; ni < 10; ++ni) {
                const int n = nh + ni * 4;
                const float4* xr = (const float4*)(x_lds + n * FIN + kh * 32);
                float a = 0.f;
#pragma unroll
                for (int i = 0; i < 8; ++i) {
                    const float4 xv = xr[i];
                    a += xv.x * wreg[4*i] + xv.y * wreg[4*i+1]
                       + xv.z * wreg[4*i+2] + xv.w * wreg[4*i+3];
                }
                acc[ni] += a;
            }
        }
        const float as = a_src[co], ad = a_dst[co];
        const int head = co >> 5;
#pragma unroll
        for (int ni = 0; ni < 10; ++ni) {
            const int n = nh + ni * 4;
            h_lds[n * Cc + co] = acc[ni];
            float es = acc[ni] * as;
            float ed = acc[ni] * ad;
#pragma unroll
            for (int off = 1; off < 32; off <<= 1) {
                es += __shfl_xor(es, off, 32);
                ed += __shfl_xor(ed, off, 32);
            }
            if (l32 == 0) {
                e_lds[n * Hh + head]           = es;
                e_lds[Nn * Hh + n * Hh + head] = ed;
            }
        }
    }
    __syncthreads();   // x_lds dead from here; smem reused for attn/g

    // ---- attention softmax for target nodes n<7, all 4 heads ----
    if (tid < NT * Hh) {
        const int n  = tid >> 2;
        const int hh = tid & 3;
        const float es = e_lds[n * Hh + hh];
        float sc[Nn];
        float mx = -1e30f;
#pragma unroll
        for (int j = 0; j < Nn; ++j) {
            float s = es + e_lds[Nn * Hh + j * Hh + hh];
            s = (s > 0.f) ? s : 0.2f * s;
            if (adj[n * Nn + j] == 0.0f) s = -1e9f;
            sc[j] = s;
            mx = fmaxf(mx, s);
        }
        float sum = 0.f;
#pragma unroll
        for (int j = 0; j < Nn; ++j) { const float p = expf(sc[j] - mx); sc[j] = p; sum += p; }
        const float inv = 1.0f / sum;
#pragma unroll
        for (int j = 0; j < Nn; ++j)
            attn_lds[(n * Hh + hh) * Nn + j] = sc[j] * inv;
    }
    __syncthreads();

    // ---- gat[n][c] = sum_j attn[n][h][j] * h[j][c] ----
    for (int idx = tid; idx < NT * Cc; idx += 512) {
        const int n  = idx >> 7;
        const int c  = idx & 127;
        const int hh = c >> 5;
        const float* ap = attn_lds + (n * Hh + hh) * Nn;
        float acc = 0.f;
#pragma unroll
        for (int j = 0; j < Nn; ++j)
            acc += ap[j] * h_lds[j * Cc + c];
        g_lds[idx] = acc;
    }
    __syncthreads();

    // ---- LayerNorm + write seq (panel order) ----
    if (tid < NT * 32) {
        const int n = tid >> 5, lane = tid & 31;
        const float4 v = ((const float4*)(g_lds + n * Cc))[lane];
        float s  = v.x + v.y + v.z + v.w;
        float sq = v.x*v.x + v.y*v.y + v.z*v.z + v.w*v.w;
#pragma unroll
        for (int off = 16; off; off >>= 1) {
            s  += __shfl_xor(s, off, 32);
            sq += __shfl_xor(sq, off, 32);
        }
        const float mu   = s * (1.0f / Cc);
        const float rstd = rsqrtf(sq * (1.0f / Cc) - mu * mu + 1e-5f);
        const float4 gg = ((const float4*)ln_g)[lane];
        const float4 bb = ((const float4*)ln_b)[lane];
        float o0 = (v.x - mu) * rstd * gg.x + bb.x;
        float o1 = (v.y - mu) * rstd * gg.y + bb.y;
        float o2 = (v.z - mu) * rstd * gg.z + bb.z;
        float o3 = (v.w - mu) * rstd * gg.w + bb.w;
        const int r = b * NT + n;
        ushort4 uh, ul;
        split_bf16(o0, uh.x, ul.x);
        split_bf16(o1, uh.y, ul.y);
        split_bf16(o2, uh.z, ul.z);
        split_bf16(o3, uh.w, ul.w);
        // co0 = lane*4 -> panel p = (lane>>2)*2 + ((lane>>1)&1), j0 = (lane&1)*4
        const int p  = (lane >> 2) * 2 + ((lane >> 1) & 1);
        const int j0 = (lane & 1) * 4;
        const size_t off = ((size_t)(r * 16 + p) * WT + tau) * 8 + j0;
        *(ushort4*)(seq_hi + off) = uh;
        *(ushort4*)(seq_lo + off) = ul;
    }
}

// ---------------------------------------------------------------------------
// Kernel 2: per row r: TCN via split-bf16 MFMA (32x32x16), activations in
// fragment-panel LDS layout (conflict-free A reads).
// ---------------------------------------------------------------------------
__device__ __forceinline__ void conv_mfma(
    const ushort* in_hi, const ushort* in_lo,
    ushort* out_hi, ushort* out_lo,
    const ushort* __restrict__ wbh, const ushort* __restrict__ wbl,  // phase base
    const float* __restrict__ psb, const float* __restrict__ pss,
    const float* __restrict__ psh,                                   // phase base
    const int tau0, const int d, const int mt, const int nt,
    const int lane, const bool residual)
{
    const int m  = lane & 31;
    const int q2 = lane >> 5;
    const int co = nt * 32 + m;

    f32x16 acc;
#pragma unroll
    for (int i = 0; i < 16; ++i) acc[i] = 0.f;

    const int mbase = mt * 32 + m;
    for (int ks = 0; ks < 24; ++ks) {
        const int kk = ks >> 3;
        int rowA = mbase - (2 - kk) * d;
        rowA = rowA < 0 ? 0 : rowA;           // clamped rows feed discarded regs
        const int aoff = (((ks & 7) << 1) + q2) * PSTRIDE + rowA * 8;
        const short8 ah = *(const short8*)(in_hi + aoff);
        const short8 al = *(const short8*)(in_lo + aoff);
        const size_t wo = ((size_t)(nt * 24 + ks) * 64 + lane) * 8;
        const short8 bh = *(const short8*)(wbh + wo);
        const short8 bl = *(const short8*)(wbl + wo);
        acc = __builtin_amdgcn_mfma_f32_32x32x16_bf16(ah, bh, acc, 0, 0, 0);
        acc = __builtin_amdgcn_mfma_f32_32x32x16_bf16(al, bh, acc, 0, 0, 0);
        acc = __builtin_amdgcn_mfma_f32_32x32x16_bf16(ah, bl, acc, 0, 0, 0);
    }

    const float bsv = psb[co], scv = pss[co], shv = psh[co];
    const int colb = ((co >> 4) * 2 + ((co >> 3) & 1)) * PSTRIDE + (co & 7);
#pragma unroll
    for (int reg = 0; reg < 16; ++reg) {
        const int row = (reg & 3) + 8 * (reg >> 2) + 4 * q2;
        const int tau = mt * 32 + row;
        if (tau >= tau0 && tau <= 60) {
            float v = (acc[reg] + bsv) * scv + shv;
            v = gelu_exact(v);
            const int off = colb + tau * 8;
            if (residual) {
                const float rc = b2f(out_hi[off]) + b2f(out_lo[off]);
                v = gelu_exact(v + rc);
            }
            ushort uh, ul; split_bf16(v, uh, ul);
            out_hi[off] = uh; out_lo[off] = ul;
        }
    }
}

__global__ __launch_bounds__(512, 4) void tcn_head_kernel(
    const char* __restrict__ ws,
    const float* __restrict__ f1w, const float* __restrict__ f1b,
    const float* __restrict__ f2w, const float* __restrict__ f2b,
    float* __restrict__ out)
{
    __shared__ __align__(16) ushort cur_hi[16 * PSTRIDE];
    __shared__ __align__(16) ushort cur_lo[16 * PSTRIDE];
    __shared__ __align__(16) ushort o1_hi [16 * PSTRIDE];
    __shared__ __align__(16) ushort o1_lo [16 * PSTRIDE];
    __shared__ float red[FC];

    const int tid = threadIdx.x;
    const int r   = blockIdx.x;

    const ushort* seq_hi = (const ushort*)(ws + SEQHI_OFF);
    const ushort* seq_lo = (const ushort*)(ws + SEQLO_OFF);
    const ushort* WBH    = (const ushort*)(ws + WBH_OFF);
    const ushort* WBL    = (const ushort*)(ws + WBL_OFF);
    const float*  PSB    = (const float*)(ws + PSB_OFF);
    const float*  PSS    = (const float*)(ws + PSS_OFF);
    const float*  PSH    = (const float*)(ws + PSH_OFF);

    // stage seq row (16 panels x 61 rows x 8) into padded LDS panels
    {
        const size_t base = (size_t)r * (16 * WT * 8);
        for (int i = tid; i < 16 * WT; i += 512) {
            const int p = i / WT, row = i - p * WT;
            const int dst = p * PSTRIDE + row * 8;
            *(uint4*)(cur_hi + dst) = *(const uint4*)(seq_hi + base + i * 8);
            *(uint4*)(cur_lo + dst) = *(const uint4*)(seq_lo + base + i * 8);
        }
    }
    __syncthreads();

    const int wave = tid >> 6;
    const int lane = tid & 63;
    const int nt   = wave & 3;
    const int mt   = wave >> 2;

    const int tau0_1[4] = {2, 8, 20, 44};
    const int tau0_2[4] = {4, 12, 28, 60};

#pragma unroll
    for (int l = 0; l < 4; ++l) {
        const int d  = 1 << l;
        const int p1 = 2 * l, p2 = 2 * l + 1;
        conv_mfma(cur_hi, cur_lo, o1_hi, o1_lo,
                  WBH + (size_t)p1 * WPHASE_US, WBL + (size_t)p1 * WPHASE_US,
                  PSB + p1 * Cc, PSS + p1 * Cc, PSH + p1 * Cc,
                  tau0_1[l], d, mt, nt, lane, false);
        __syncthreads();
        conv_mfma(o1_hi, o1_lo, cur_hi, cur_lo,
                  WBH + (size_t)p2 * WPHASE_US, WBL + (size_t)p2 * WPHASE_US,
                  PSB + p2 * Cc, PSS + p2 * Cc, PSH + p2 * Cc,
                  tau0_2[l], d, mt, nt, lane, true);
        __syncthreads();
        vstart_unused:;
    }

    // ---- fused head on cur row 60 ----
    if (tid < FC) {
        const float4* wr = (const float4*)(f1w + tid * Cc);
        float acc = 0.f;
#pragma unroll
        for (int i = 0; i < Cc / 4; ++i) {
            const float4 wv = wr[i];
            const int ci0 = i * 4;
            const int off = ((ci0 >> 4) * 2 + ((ci0 >> 3) & 1)) * PSTRIDE
                          + 60 * 8 + (ci0 & 7);
            acc += wv.x * (b2f(cur_hi[off + 0]) + b2f(cur_lo[off + 0]))
                 + wv.y * (b2f(cur_hi[off + 1]) + b2f(cur_lo[off + 1]))
                 + wv.z * (b2f(cur_hi[off + 2]) + b2f(cur_lo[off + 2]))
                 + wv.w * (b2f(cur_hi[off + 3]) + b2f(cur_lo[off + 3]));
        }
        red[tid] = gelu_exact(acc + f1b[tid]) * f2w[tid];
    }
    __syncthreads();
    if (tid < 64) {
        float v = red[tid] + red[tid + 64];
#pragma unroll
        for (int off = 32; off; off >>= 1) v += __shfl_xor(v, off, 64);
        if (tid == 0) out[r] = v + f2b[0];
    }
}

// ---------------------------------------------------------------------------
extern "C" void kernel_launch(void* const* d_in, const int* in_sizes, int n_in,
                              void* d_out, int out_size, void* d_ws, size_t ws_size,
                              hipStream_t stream) {
    const float* x     = (const float*)d_in[0];
    const float* adj   = (const float*)d_in[1];
    const float* gat_w = (const float*)d_in[2];
    const float* a_src = (const float*)d_in[3];
    const float* a_dst = (const float*)d_in[4];
    const float* ln_g  = (const float*)d_in[5];
    const float* ln_b  = (const float*)d_in[6];
    const float* c1w   = (const float*)d_in[7];
    const float* c1b   = (const float*)d_in[8];
    const float* c2w   = (const float*)d_in[9];
    const float* c2b   = (const float*)d_in[10];
    const float* bn1s  = (const float*)d_in[11];
    const float* bn1b  = (const float*)d_in[12];
    const float* bn1m  = (const float*)d_in[13];
    const float* bn1v  = (const float*)d_in[14];
    const float* bn2s  = (const float*)d_in[15];
    const float* bn2b  = (const float*)d_in[16];
    const float* bn2m  = (const float*)d_in[17];
    const float* bn2v  = (const float*)d_in[18];
    const float* f1w   = (const float*)d_in[19];
    const float* f1b   = (const float*)d_in[20];
    const float* f2w   = (const float*)d_in[21];
    const float* f2b   = (const float*)d_in[22];

    char* ws = (char*)d_ws;

    prep_kernel<<<193, 256, 0, stream>>>(c1w, c1b, c2w, c2b,
        bn1s, bn1b, bn1m, bn1v, bn2s, bn2b, bn2m, bn2v, ws);

    gat_ln_kernel<<<Bb * WT, 512, 0, stream>>>(
        x, adj, gat_w, a_src, a_dst, ln_g, ln_b,
        (ushort*)(ws + SEQHI_OFF), (ushort*)(ws + SEQLO_OFF));

    tcn_head_kernel<<<Bb * NT, 512, 0, stream>>>(
        ws, f1w, f1b, f2w, f2b, (float*)d_out);
}

// Round 6
// 427.457 us; speedup vs baseline: 5.9686x; 5.9686x over previous
//
#include <hip/hip_runtime.h>
#include <hip/hip_bf16.h>
#include <math.h>

// Shapes (fixed by the problem)
#define Bb   64
#define Nn   40
#define Ww   256
#define FIN  64
#define Hh   4
#define Dd   32
#define Cc   128
#define NT   7
#define FC   128
#define WT   61          // receptive field of the TCN stack
#define W0   195         // first needed global timestep (255-60)
#define PSTRIDE 520      // LDS panel stride (ushorts): 64 rows x 8 + 8 pad
#define HS   132         // h_lds row stride (floats)

// workspace layout (byte offsets). seq stored as split bf16 (hi+lo),
// global layout per row r: [16 panels][61 rows][8 ushorts]
#define SEQHI_OFF  0u
#define SEQ_BYTES  (448u * WT * Cc * 2u)             // 6,995,968 B
#define SEQLO_OFF  (SEQHI_OFF + SEQ_BYTES)
#define WBH_OFF    (SEQLO_OFF + SEQ_BYTES)           // conv w frag bf16 hi
#define WB_BYTES   (8u * 4u * 24u * 64u * 8u * 2u)   // 786,432 B
#define WBL_OFF    (WBH_OFF + WB_BYTES)
#define PSB_OFF    (WBL_OFF + WB_BYTES)              // f32 bias[8][128]
#define PSS_OFF    (PSB_OFF + 4096u)                 // f32 scale[8][128]
#define PSH_OFF    (PSS_OFF + 4096u)                 // f32 shift[8][128]
#define WGH_OFF    (PSH_OFF + 4096u)                 // gat_w frag bf16 hi (16 KB)
#define WGL_OFF    (WGH_OFF + 16384u)                // gat_w frag bf16 lo (16 KB)
#define WPHASE_US  49152u                            // ushorts per phase in WBH/WBL

typedef __attribute__((ext_vector_type(8)))  short short8;
typedef __attribute__((ext_vector_type(16))) float f32x16;

__device__ __forceinline__ float gelu_exact(float v) {
    return 0.5f * v * (1.0f + erff(v * 0.70710678118654752440f));
}
__device__ __forceinline__ float b2f(ushort u) {
    union { uint i; float f; } c; c.i = ((uint)u) << 16; return c.f;
}
__device__ __forceinline__ void split_bf16(float v, ushort& h, ushort& l) {
    __hip_bfloat16 bh = __float2bfloat16(v);
    float fh = __bfloat162float(bh);
    __hip_bfloat16 bl = __float2bfloat16(v - fh);
    h = *(ushort*)&bh; l = *(ushort*)&bl;
}

// ---------------------------------------------------------------------------
// Prep: conv weights -> bf16 hi/lo in MFMA-B-fragment order; BN fold;
// gat_w -> bf16 hi/lo B-fragments (4 nt x 4 ks x 64 lanes x 8).
// ---------------------------------------------------------------------------
__global__ __launch_bounds__(256) void prep_kernel(
    const float* __restrict__ c1w, const float* __restrict__ c1b,
    const float* __restrict__ c2w, const float* __restrict__ c2b,
    const float* __restrict__ bn1s, const float* __restrict__ bn1b,
    const float* __restrict__ bn1m, const float* __restrict__ bn1v,
    const float* __restrict__ bn2s, const float* __restrict__ bn2b,
    const float* __restrict__ bn2m, const float* __restrict__ bn2v,
    const float* __restrict__ gat_w,
    char* __restrict__ ws)
{
    if (blockIdx.x < 192) {
        const int t = blockIdx.x * 256 + threadIdx.x;   // [0, 49152)
        const int lane  = t & 63;
        const int kstep = (t >> 6) % 24;
        const int nt    = ((t >> 6) / 24) & 3;
        const int p     = (t >> 6) / 96;
        const int l = p >> 1, cv = p & 1;
        const int co = nt * 32 + (lane & 31);
        const float* wsrc = cv ? c2w : c1w;
        ushort* wbh = (ushort*)(ws + WBH_OFF);
        ushort* wbl = (ushort*)(ws + WBL_OFF);
#pragma unroll
        for (int j = 0; j < 8; ++j) {
            const int k  = kstep * 16 + ((lane >> 5) << 3) + j;
            const int kk = k >> 7, ci = k & 127;
            const float w = wsrc[((size_t)(l * Cc + co) * Cc + ci) * 3 + kk];
            ushort h, lo; split_bf16(w, h, lo);
            wbh[(size_t)t * 8 + j] = h;
            wbl[(size_t)t * 8 + j] = lo;
        }
    } else if (blockIdx.x == 192) {
        float* psb = (float*)(ws + PSB_OFF);
        float* pss = (float*)(ws + PSS_OFF);
        float* psh = (float*)(ws + PSH_OFF);
        for (int idx = threadIdx.x; idx < 1024; idx += 256) {
            const int p = idx >> 7, co = idx & 127;
            const int l = p >> 1, cv = p & 1;
            const int lc = l * Cc + co;
            const float s  = cv ? bn2s[lc] : bn1s[lc];
            const float bb = cv ? bn2b[lc] : bn1b[lc];
            const float m  = cv ? bn2m[lc] : bn1m[lc];
            const float vv = cv ? bn2v[lc] : bn1v[lc];
            const float cb = cv ? c2b[lc] : c1b[lc];
            const float scale = s * rsqrtf(vv + 1e-5f);
            pss[idx] = scale;
            psh[idx] = bb - m * scale;
            psb[idx] = cb;
        }
    } else {
        // gat_w fragments: chunk t = (nt*4+ks)*64+lane, elem j:
        //   k = ks*16 + (lane>>5)*8 + j, co = nt*32 + (lane&31)
        ushort* wgh = (ushort*)(ws + WGH_OFF);
        ushort* wgl = (ushort*)(ws + WGL_OFF);
#pragma unroll
        for (int it = 0; it < 4; ++it) {
            const int t = it * 256 + threadIdx.x;     // [0,1024)
            const int lane = t & 63;
            const int ks   = (t >> 6) & 3;
            const int nt   = t >> 8;
            const int co   = nt * 32 + (lane & 31);
#pragma unroll
            for (int j = 0; j < 8; ++j) {
                const int k = ks * 16 + ((lane >> 5) << 3) + j;
                ushort h, lo; split_bf16(gat_w[co * FIN + k], h, lo);
                wgh[t * 8 + j] = h;
                wgl[t * 8 + j] = lo;
            }
        }
    }
}

// ---------------------------------------------------------------------------
// Kernel 1: per (b, tau): h-GEMM via split-bf16 MFMA (32x32x16), then
// e/softmax/gather/LN in f32. 256 threads = 4 waves (wave nt owns co-tile).
// ---------------------------------------------------------------------------
__global__ __launch_bounds__(256) void gat_ln_kernel(
    const float* __restrict__ x, const float* __restrict__ adj,
    const char* __restrict__ ws_ro,
    const float* __restrict__ a_src, const float* __restrict__ a_dst,
    const float* __restrict__ ln_g, const float* __restrict__ ln_b,
    ushort* __restrict__ seq_hi, ushort* __restrict__ seq_lo)
{
    __shared__ __align__(16) ushort xa_hi[8 * PSTRIDE];   // A-frag panels
    __shared__ __align__(16) ushort xa_lo[8 * PSTRIDE];
    __shared__ __align__(16) float h_lds[Nn * HS];
    __shared__ __align__(16) float e_lds[2 * Nn * Hh];    // [s][n][h]
    __shared__ __align__(16) float attn_lds[NT * Hh * Nn];
    __shared__ __align__(16) float g_lds[NT * Cc];

    const int tid = threadIdx.x;
    const int blk = blockIdx.x;
    const int b   = blk / WT;
    const int tau = blk % WT;
    const int w   = W0 + tau;

    // ---- stage x[b,:,w,:] as bf16 hi/lo A-fragment panels ----
    // panel oc = k>>3 (8 panels), row n, 8 contiguous k. 320 items, 256 thr.
    for (int idx = tid; idx < Nn * 8; idx += 256) {
        const int n  = idx >> 3;
        const int oc = idx & 7;
        const float* src = x + ((size_t)(b * Nn + n) * Ww + w) * FIN + oc * 8;
        const float4 f0 = *(const float4*)(src);
        const float4 f1 = *(const float4*)(src + 4);
        ushort h[8], l[8];
        split_bf16(f0.x, h[0], l[0]); split_bf16(f0.y, h[1], l[1]);
        split_bf16(f0.z, h[2], l[2]); split_bf16(f0.w, h[3], l[3]);
        split_bf16(f1.x, h[4], l[4]); split_bf16(f1.y, h[5], l[5]);
        split_bf16(f1.z, h[6], l[6]); split_bf16(f1.w, h[7], l[7]);
        const int dst = oc * PSTRIDE + n * 8;
        *(uint4*)(xa_hi + dst) = *(uint4*)h;
        *(uint4*)(xa_lo + dst) = *(uint4*)l;
    }
    // zero panel rows 40..63 (consumed by acc1's discarded rows — NaN hygiene)
    for (int idx = tid; idx < 8 * (64 - Nn); idx += 256) {
        const int oc = idx / (64 - Nn);
        const int n  = Nn + idx % (64 - Nn);
        const int dst = oc * PSTRIDE + n * 8;
        uint4 z; z.x = z.y = z.z = z.w = 0u;
        *(uint4*)(xa_hi + dst) = z;
        *(uint4*)(xa_lo + dst) = z;
    }
    __syncthreads();

    // ---- MFMA h-GEMM: wave nt -> co tile nt*32; 2 M-tiles ----
    {
        const int wave = tid >> 6;
        const int lane = tid & 63;
        const int nt   = wave;
        const int q2   = lane >> 5;
        const int m32  = lane & 31;
        const ushort* WGH = (const ushort*)(ws_ro + WGH_OFF);
        const ushort* WGL = (const ushort*)(ws_ro + WGL_OFF);

        f32x16 acc0, acc1;
#pragma unroll
        for (int i = 0; i < 16; ++i) { acc0[i] = 0.f; acc1[i] = 0.f; }

#pragma unroll
        for (int ks = 0; ks < 4; ++ks) {
            const size_t wo = ((size_t)((nt * 4 + ks) * 64 + lane)) * 8;
            const short8 bh = *(const short8*)(WGH + wo);
            const short8 bl = *(const short8*)(WGL + wo);
            const int pan = (ks * 2 + q2) * PSTRIDE;
            const short8 ah0 = *(const short8*)(xa_hi + pan + m32 * 8);
            const short8 al0 = *(const short8*)(xa_lo + pan + m32 * 8);
            const short8 ah1 = *(const short8*)(xa_hi + pan + (32 + m32) * 8);
            const short8 al1 = *(const short8*)(xa_lo + pan + (32 + m32) * 8);
            acc0 = __builtin_amdgcn_mfma_f32_32x32x16_bf16(ah0, bh, acc0, 0, 0, 0);
            acc0 = __builtin_amdgcn_mfma_f32_32x32x16_bf16(al0, bh, acc0, 0, 0, 0);
            acc0 = __builtin_amdgcn_mfma_f32_32x32x16_bf16(ah0, bl, acc0, 0, 0, 0);
            acc1 = __builtin_amdgcn_mfma_f32_32x32x16_bf16(ah1, bh, acc1, 0, 0, 0);
            acc1 = __builtin_amdgcn_mfma_f32_32x32x16_bf16(al1, bh, acc1, 0, 0, 0);
            acc1 = __builtin_amdgcn_mfma_f32_32x32x16_bf16(ah1, bl, acc1, 0, 0, 0);
        }

        const int co = nt * 32 + m32;
#pragma unroll
        for (int reg = 0; reg < 16; ++reg) {
            const int n = (reg & 3) + 8 * (reg >> 2) + 4 * q2;
            h_lds[n * HS + co] = acc0[reg];
        }
#pragma unroll
        for (int reg = 0; reg < 4; ++reg) {          // only rows 32..39 valid
            const int n = 32 + reg + 4 * q2;
            if (n < Nn) h_lds[n * HS + co] = acc1[reg];
        }
    }
    __syncthreads();

    // ---- e_src/e_dst[n][h] = sum_d h[n][h*32+d] * a[h*32+d] ----
    for (int u = tid; u < 2 * Nn * Hh; u += 256) {
        const int s  = u & 1;
        const int hh = (u >> 1) & 3;
        const int n  = u >> 3;
        const float* av = (s ? a_dst : a_src) + hh * Dd;
        const float* hp = h_lds + n * HS + hh * Dd;
        float acc = 0.f;
#pragma unroll
        for (int i = 0; i < 8; ++i) {
            const float4 hv = *(const float4*)(hp + i * 4);
            const float4 avv = *(const float4*)(av + i * 4);
            acc += hv.x * avv.x + hv.y * avv.y + hv.z * avv.z + hv.w * avv.w;
        }
        e_lds[s * (Nn * Hh) + n * Hh + hh] = acc;
    }
    __syncthreads();

    // ---- attention softmax for target nodes n<7, all 4 heads ----
    if (tid < NT * Hh) {
        const int n  = tid >> 2;
        const int hh = tid & 3;
        const float es = e_lds[n * Hh + hh];
        float sc[Nn];
        float mx = -1e30f;
#pragma unroll
        for (int j = 0; j < Nn; ++j) {
            float s = es + e_lds[Nn * Hh + j * Hh + hh];
            s = (s > 0.f) ? s : 0.2f * s;
            if (adj[n * Nn + j] == 0.0f) s = -1e9f;
            sc[j] = s;
            mx = fmaxf(mx, s);
        }
        float sum = 0.f;
#pragma unroll
        for (int j = 0; j < Nn; ++j) { const float p = expf(sc[j] - mx); sc[j] = p; sum += p; }
        const float inv = 1.0f / sum;
#pragma unroll
        for (int j = 0; j < Nn; ++j)
            attn_lds[(n * Hh + hh) * Nn + j] = sc[j] * inv;
    }
    __syncthreads();

    // ---- gather: gat[n][c0..c0+3] = sum_j attn * h[j][c0..] ----
    if (tid < NT * 32) {
        const int n    = tid >> 5;
        const int cq   = tid & 31;
        const int c0   = cq * 4;
        const int head = cq >> 3;
        const float* ap = attn_lds + (n * Hh + head) * Nn;
        float4 acc = make_float4(0.f, 0.f, 0.f, 0.f);
        for (int j = 0; j < Nn; ++j) {
            const float a = ap[j];
            const float4 hv = *(const float4*)(h_lds + j * HS + c0);
            acc.x += a * hv.x; acc.y += a * hv.y;
            acc.z += a * hv.z; acc.w += a * hv.w;
        }
        *(float4*)(g_lds + n * Cc + c0) = acc;
    }
    __syncthreads();

    // ---- LayerNorm + write seq (K2 panel order) ----
    if (tid < NT * 32) {
        const int n = tid >> 5, lane = tid & 31;
        const float4 v = ((const float4*)(g_lds + n * Cc))[lane];
        float s  = v.x + v.y + v.z + v.w;
        float sq = v.x*v.x + v.y*v.y + v.z*v.z + v.w*v.w;
#pragma unroll
        for (int off = 16; off; off >>= 1) {
            s  += __shfl_xor(s, off, 32);
            sq += __shfl_xor(sq, off, 32);
        }
        const float mu   = s * (1.0f / Cc);
        const float rstd = rsqrtf(sq * (1.0f / Cc) - mu * mu + 1e-5f);
        const float4 gg = ((const float4*)ln_g)[lane];
        const float4 bb = ((const float4*)ln_b)[lane];
        float o0 = (v.x - mu) * rstd * gg.x + bb.x;
        float o1 = (v.y - mu) * rstd * gg.y + bb.y;
        float o2 = (v.z - mu) * rstd * gg.z + bb.z;
        float o3 = (v.w - mu) * rstd * gg.w + bb.w;
        const int r = b * NT + n;
        ushort4 uh, ul;
        split_bf16(o0, uh.x, ul.x);
        split_bf16(o1, uh.y, ul.y);
        split_bf16(o2, uh.z, ul.z);
        split_bf16(o3, uh.w, ul.w);
        // co0 = lane*4 -> panel p = (lane>>2)*2 + ((lane>>1)&1), j0 = (lane&1)*4
        const int p  = (lane >> 2) * 2 + ((lane >> 1) & 1);
        const int j0 = (lane & 1) * 4;
        const size_t off = ((size_t)(r * 16 + p) * WT + tau) * 8 + j0;
        *(ushort4*)(seq_hi + off) = uh;
        *(ushort4*)(seq_lo + off) = ul;
    }
}

// ---------------------------------------------------------------------------
// Kernel 2: per row r: TCN via split-bf16 MFMA (32x32x16), activations in
// fragment-panel LDS layout (conflict-free A reads).
// ---------------------------------------------------------------------------
__device__ __forceinline__ void conv_mfma(
    const ushort* in_hi, const ushort* in_lo,
    ushort* out_hi, ushort* out_lo,
    const ushort* __restrict__ wbh, const ushort* __restrict__ wbl,
    const float* __restrict__ psb, const float* __restrict__ pss,
    const float* __restrict__ psh,
    const int tau0, const int d, const int mt, const int nt,
    const int lane, const bool residual)
{
    const int m  = lane & 31;
    const int q2 = lane >> 5;
    const int co = nt * 32 + m;

    f32x16 acc;
#pragma unroll
    for (int i = 0; i < 16; ++i) acc[i] = 0.f;

    const int mbase = mt * 32 + m;
    for (int ks = 0; ks < 24; ++ks) {
        const int kk = ks >> 3;
        int rowA = mbase - (2 - kk) * d;
        rowA = rowA < 0 ? 0 : rowA;           // clamped rows feed discarded regs
        const int aoff = (((ks & 7) << 1) + q2) * PSTRIDE + rowA * 8;
        const short8 ah = *(const short8*)(in_hi + aoff);
        const short8 al = *(const short8*)(in_lo + aoff);
        const size_t wo = ((size_t)(nt * 24 + ks) * 64 + lane) * 8;
        const short8 bh = *(const short8*)(wbh + wo);
        const short8 bl = *(const short8*)(wbl + wo);
        acc = __builtin_amdgcn_mfma_f32_32x32x16_bf16(ah, bh, acc, 0, 0, 0);
        acc = __builtin_amdgcn_mfma_f32_32x32x16_bf16(al, bh, acc, 0, 0, 0);
        acc = __builtin_amdgcn_mfma_f32_32x32x16_bf16(ah, bl, acc, 0, 0, 0);
    }

    const float bsv = psb[co], scv = pss[co], shv = psh[co];
    const int colb = ((co >> 4) * 2 + ((co >> 3) & 1)) * PSTRIDE + (co & 7);
#pragma unroll
    for (int reg = 0; reg < 16; ++reg) {
        const int row = (reg & 3) + 8 * (reg >> 2) + 4 * q2;
        const int tau = mt * 32 + row;
        if (tau >= tau0 && tau <= 60) {
            float v = (acc[reg] + bsv) * scv + shv;
            v = gelu_exact(v);
            const int off = colb + tau * 8;
            if (residual) {
                const float rc = b2f(out_hi[off]) + b2f(out_lo[off]);
                v = gelu_exact(v + rc);
            }
            ushort uh, ul; split_bf16(v, uh, ul);
            out_hi[off] = uh; out_lo[off] = ul;
        }
    }
}

__global__ __launch_bounds__(512) void tcn_head_kernel(
    const char* __restrict__ ws,
    const float* __restrict__ f1w, const float* __restrict__ f1b,
    const float* __restrict__ f2w, const float* __restrict__ f2b,
    float* __restrict__ out)
{
    __shared__ __align__(16) ushort cur_hi[16 * PSTRIDE];
    __shared__ __align__(16) ushort cur_lo[16 * PSTRIDE];
    __shared__ __align__(16) ushort o1_hi [16 * PSTRIDE];
    __shared__ __align__(16) ushort o1_lo [16 * PSTRIDE];
    __shared__ float red[FC];

    const int tid = threadIdx.x;
    const int r   = blockIdx.x;

    const ushort* seq_hi = (const ushort*)(ws + SEQHI_OFF);
    const ushort* seq_lo = (const ushort*)(ws + SEQLO_OFF);
    const ushort* WBH    = (const ushort*)(ws + WBH_OFF);
    const ushort* WBL    = (const ushort*)(ws + WBL_OFF);
    const float*  PSB    = (const float*)(ws + PSB_OFF);
    const float*  PSS    = (const float*)(ws + PSS_OFF);
    const float*  PSH    = (const float*)(ws + PSH_OFF);

    {
        const size_t base = (size_t)r * (16 * WT * 8);
        for (int i = tid; i < 16 * WT; i += 512) {
            const int p = i / WT, row = i - p * WT;
            const int dst = p * PSTRIDE + row * 8;
            *(uint4*)(cur_hi + dst) = *(const uint4*)(seq_hi + base + i * 8);
            *(uint4*)(cur_lo + dst) = *(const uint4*)(seq_lo + base + i * 8);
        }
    }
    __syncthreads();

    const int wave = tid >> 6;
    const int lane = tid & 63;
    const int nt   = wave & 3;
    const int mt   = wave >> 2;

    const int tau0_1[4] = {2, 8, 20, 44};
    const int tau0_2[4] = {4, 12, 28, 60};

#pragma unroll
    for (int l = 0; l < 4; ++l) {
        const int d  = 1 << l;
        const int p1 = 2 * l, p2 = 2 * l + 1;
        conv_mfma(cur_hi, cur_lo, o1_hi, o1_lo,
                  WBH + (size_t)p1 * WPHASE_US, WBL + (size_t)p1 * WPHASE_US,
                  PSB + p1 * Cc, PSS + p1 * Cc, PSH + p1 * Cc,
                  tau0_1[l], d, mt, nt, lane, false);
        __syncthreads();
        conv_mfma(o1_hi, o1_lo, cur_hi, cur_lo,
                  WBH + (size_t)p2 * WPHASE_US, WBL + (size_t)p2 * WPHASE_US,
                  PSB + p2 * Cc, PSS + p2 * Cc, PSH + p2 * Cc,
                  tau0_2[l], d, mt, nt, lane, true);
        __syncthreads();
    }

    // ---- fused head on cur row 60 ----
    if (tid < FC) {
        const float4* wr = (const float4*)(f1w + tid * Cc);
        float acc = 0.f;
#pragma unroll
        for (int i = 0; i < Cc / 4; ++i) {
            const float4 wv = wr[i];
            const int ci0 = i * 4;
            const int off = ((ci0 >> 4) * 2 + ((ci0 >> 3) & 1)) * PSTRIDE
                          + 60 * 8 + (ci0 & 7);
            acc += wv.x * (b2f(cur_hi[off + 0]) + b2f(cur_lo[off + 0]))
                 + wv.y * (b2f(cur_hi[off + 1]) + b2f(cur_lo[off + 1]))
                 + wv.z * (b2f(cur_hi[off + 2]) + b2f(cur_lo[off + 2]))
                 + wv.w * (b2f(cur_hi[off + 3]) + b2f(cur_lo[off + 3]));
        }
        red[tid] = gelu_exact(acc + f1b[tid]) * f2w[tid];
    }
    __syncthreads();
    if (tid < 64) {
        float v = red[tid] + red[tid + 64];
#pragma unroll
        for (int off = 32; off; off >>= 1) v += __shfl_xor(v, off, 64);
        if (tid == 0) out[r] = v + f2b[0];
    }
}

// ---------------------------------------------------------------------------
extern "C" void kernel_launch(void* const* d_in, const int* in_sizes, int n_in,
                              void* d_out, int out_size, void* d_ws, size_t ws_size,
                              hipStream_t stream) {
    const float* x     = (const float*)d_in[0];
    const float* adj   = (const float*)d_in[1];
    const float* gat_w = (const float*)d_in[2];
    const float* a_src = (const float*)d_in[3];
    const float* a_dst = (const float*)d_in[4];
    const float* ln_g  = (const float*)d_in[5];
    const float* ln_b  = (const float*)d_in[6];
    const float* c1w   = (const float*)d_in[7];
    const float* c1b   = (const float*)d_in[8];
    const float* c2w   = (const float*)d_in[9];
    const float* c2b   = (const float*)d_in[10];
    const float* bn1s  = (const float*)d_in[11];
    const float* bn1b  = (const float*)d_in[12];
    const float* bn1m  = (const float*)d_in[13];
    const float* bn1v  = (const float*)d_in[14];
    const float* bn2s  = (const float*)d_in[15];
    const float* bn2b  = (const float*)d_in[16];
    const float* bn2m  = (const float*)d_in[17];
    const float* bn2v  = (const float*)d_in[18];
    const float* f1w   = (const float*)d_in[19];
    const float* f1b   = (const float*)d_in[20];
    const float* f2w   = (const float*)d_in[21];
    const float* f2b   = (const float*)d_in[22];

    char* ws = (char*)d_ws;

    prep_kernel<<<194, 256, 0, stream>>>(c1w, c1b, c2w, c2b,
        bn1s, bn1b, bn1m, bn1v, bn2s, bn2b, bn2m, bn2v, gat_w, ws);

    gat_ln_kernel<<<Bb * WT, 256, 0, stream>>>(
        x, adj, ws, a_src, a_dst, ln_g, ln_b,
        (ushort*)(ws + SEQHI_OFF), (ushort*)(ws + SEQLO_OFF));

    tcn_head_kernel<<<Bb * NT, 512, 0, stream>>>(
        ws, f1w, f1b, f2w, f2b, (float*)d_out);
}